// Round 1
// baseline (1009.934 us; speedup 1.0000x reference)
//
#include <hip/hip_runtime.h>
#include <math.h>

#define NODES 64
#define NSTEPS 64
#define LDH 68            // padded row stride (floats) for 64(+1)-wide LDS matrices
#define EPG 1024          // edges per graph
#define NTHREADS 320      // 4 tile waves + 1 x-column wave
#define NBLOCKS 256       // one block per graph

// acc[rr][cc] += sum_{k=0}^{K-1} A[(arow+rr)*lda + k] * B[k*ldb + j4+cc]
template<int K>
__device__ __forceinline__ void mm4x4_acc(float acc[4][4],
                                          const float* __restrict__ A, int lda, int arow,
                                          const float* __restrict__ Bm, int ldb, int j4)
{
#pragma unroll 2
  for (int kc = 0; kc < K; kc += 4) {
    float av[4][4];
    float bv[4][4];
#pragma unroll
    for (int rr = 0; rr < 4; ++rr) {
      const float4 t = *(const float4*)(A + (arow + rr) * lda + kc);
      av[rr][0] = t.x; av[rr][1] = t.y; av[rr][2] = t.z; av[rr][3] = t.w;
    }
#pragma unroll
    for (int kk = 0; kk < 4; ++kk) {
      const float4 t = *(const float4*)(Bm + (kc + kk) * ldb + j4);
      bv[kk][0] = t.x; bv[kk][1] = t.y; bv[kk][2] = t.z; bv[kk][3] = t.w;
    }
#pragma unroll
    for (int rr = 0; rr < 4; ++rr)
#pragma unroll
      for (int cc = 0; cc < 4; ++cc) {
        float s = acc[rr][cc];
#pragma unroll
        for (int kk = 0; kk < 4; ++kk) s += av[rr][kk] * bv[kk][cc];
        acc[rr][cc] = s;
      }
  }
}

// tail term k = 64 of the augmented (65-deep) matmul: A col 64 (x-part) * B row 64 (wA row)
__device__ __forceinline__ void mm_tail65(float acc[4][4],
                                          const float* __restrict__ A, int arow,
                                          const float* __restrict__ Bm, int j4)
{
  const float4 bt = *(const float4*)(Bm + 64 * 64 + j4);
  float bvv[4] = {bt.x, bt.y, bt.z, bt.w};
#pragma unroll
  for (int rr = 0; rr < 4; ++rr) {
    const float a = A[(arow + rr) * LDH + 64];
#pragma unroll
    for (int cc = 0; cc < 4; ++cc) acc[rr][cc] += a * bvv[cc];
  }
}

// OUT = (MODE ? 2*(Lg@V) - SUB : Lg@V) on this thread's 4x4 tile (cols 0..63)
template<int MODE>
__device__ __forceinline__ void lapply_tile(const float* __restrict__ Lg,
                                            const float* __restrict__ V,
                                            const float* __restrict__ SUB,
                                            float* __restrict__ OUT,
                                            int i4, int j4)
{
  float m[4][4] = {};
  mm4x4_acc<64>(m, Lg, LDH, i4, V, LDH, j4);
#pragma unroll
  for (int rr = 0; rr < 4; ++rr) {
    float4 o;
    if (MODE) {
      const float4 s = *(const float4*)(SUB + (i4 + rr) * LDH + j4);
      o.x = 2.f * m[rr][0] - s.x;
      o.y = 2.f * m[rr][1] - s.y;
      o.z = 2.f * m[rr][2] - s.z;
      o.w = 2.f * m[rr][3] - s.w;
    } else {
      o.x = m[rr][0]; o.y = m[rr][1]; o.z = m[rr][2]; o.w = m[rr][3];
    }
    *(float4*)(OUT + (i4 + rr) * LDH + j4) = o;
  }
}

// x-column (col 64) L-apply, done by wave 4; uses transposed Lg for conflict-free reads
template<int MODE>
__device__ __forceinline__ void lapply_col(const float* __restrict__ LgT,
                                           const float* __restrict__ V,
                                           const float* __restrict__ SUB,
                                           float* __restrict__ OUT,
                                           int r)
{
  float m = 0.f;
#pragma unroll 4
  for (int k = 0; k < 64; ++k) m += LgT[k * NODES + r] * V[k * LDH + 64];
  const float v = MODE ? (2.f * m - SUB[r * LDH + 64]) : m;
  OUT[r * LDH + 64] = v;
}

__global__ __launch_bounds__(NTHREADS, 1)
void gcrnn_gcn_fused(const float* __restrict__ x,     // [N=16384][64]
                     const float* __restrict__ ew,    // [E=262144]
                     const float* __restrict__ wA,    // [4][1][64]
                     const float* __restrict__ bA,    // [64]
                     const float* __restrict__ wB,    // [4][64][64]
                     const float* __restrict__ bB,    // [64]
                     const float* __restrict__ w1,    // [64][64]
                     const float* __restrict__ b1,    // [64]
                     const float* __restrict__ w2,    // [64][32]
                     const float* __restrict__ b2,    // [32]
                     const float* __restrict__ wfc,   // [2048][4]
                     const float* __restrict__ bfc,   // [4]
                     const int* __restrict__ esrc,    // [E]
                     const int* __restrict__ edst,    // [E]
                     float* __restrict__ out)         // [256][4]
{
  __shared__ float sLg[NODES * LDH];      // dense Laplacian (row-major, padded)
  __shared__ float sLgT[NODES * NODES];   // transposed copy (for x-column wave)
  __shared__ float sH[NODES * LDH];       // [h | x_t] augmented state, col 64 = x_t
  __shared__ float sT1[NODES * LDH];
  __shared__ float sT2[NODES * LDH];
  __shared__ float sWB[4 * 65 * 64];      // augmented weights: row 64 of each = wA[k]
  __shared__ float sBsum[NODES];          // bA + bB
  __shared__ float sDeg[NODES];
  __shared__ float sDinv[NODES];
  __shared__ float sLogit[4];

  const int b = blockIdx.x;
  const int tid = threadIdx.x;
  const int gbase = b * NODES;
  const int ebase = b * EPG;

  const bool isTile = tid < 256;
  const int i4 = ((tid >> 4) & 15) * 4;
  const int j4 = (tid & 15) * 4;
  const int rcol = tid & 63;

  // ---------- Phase 0: zero LDS, stage weights ----------
  for (int idx = tid; idx < NODES * LDH; idx += NTHREADS) { sLg[idx] = 0.f; sH[idx] = 0.f; }
  for (int idx = tid; idx < NODES * NODES; idx += NTHREADS) sLgT[idx] = 0.f;
  if (tid < NODES) { sDeg[tid] = 0.f; sBsum[tid] = bA[tid] + bB[tid]; }
  for (int idx = tid; idx < 4 * 65 * 64; idx += NTHREADS) {
    const int kk = idx / (65 * 64);
    const int rem = idx - kk * (65 * 64);
    const int k = rem >> 6;
    const int c = rem & 63;
    sWB[idx] = (k < 64) ? wB[(kk * 64 + k) * 64 + c] : wA[kk * 64 + c];
  }
  __syncthreads();

  // ---------- Phase 1: build dense Laplacian ----------
  // cheb degree: by SRC
  for (int e = tid; e < EPG; e += NTHREADS) {
    const int sl = esrc[ebase + e] - gbase;
    atomicAdd(&sDeg[sl], ew[ebase + e]);
  }
  __syncthreads();
  if (tid < NODES) {
    const float d = sDeg[tid];
    sDinv[tid] = (d > 0.f) ? (1.f / sqrtf(d)) : 0.f;
  }
  __syncthreads();
  for (int e = tid; e < EPG; e += NTHREADS) {
    const int sl = esrc[ebase + e] - gbase;
    const int dl = edst[ebase + e] - gbase;
    const float wl = -(sDinv[sl] * ew[ebase + e] * sDinv[dl]);
    atomicAdd(&sLg[dl * LDH + sl], wl);
    atomicAdd(&sLgT[sl * NODES + dl], wl);
  }
  __syncthreads();

  // ---------- Phase 2: T=64 step ChebConv-GRU scan ----------
#pragma unroll 1
  for (int t = 0; t < NSTEPS; ++t) {
    if (tid < NODES) sH[tid * LDH + 64] = x[(gbase + tid) * NSTEPS + t];
    __syncthreads();  // B1: x_t visible

    float acc[4][4];
    if (isTile) {
#pragma unroll
      for (int rr = 0; rr < 4; ++rr)
#pragma unroll
        for (int cc = 0; cc < 4; ++cc) acc[rr][cc] = sBsum[j4 + cc];
      // term0: [h|x] @ W0aug
      mm4x4_acc<64>(acc, sH, LDH, i4, sWB + 0 * 65 * 64, 64, j4);
      mm_tail65(acc, sH, i4, sWB + 0 * 65 * 64, j4);
      // T1 = L @ [h|x]
      lapply_tile<0>(sLg, sH, nullptr, sT1, i4, j4);
    } else {
      lapply_col<0>(sLgT, sH, nullptr, sT1, rcol);
    }
    __syncthreads();  // B2: T1 complete

    if (isTile) {
      mm4x4_acc<64>(acc, sT1, LDH, i4, sWB + 1 * 65 * 64, 64, j4);
      mm_tail65(acc, sT1, i4, sWB + 1 * 65 * 64, j4);
      lapply_tile<1>(sLg, sT1, sH, sT2, i4, j4);   // T2 = 2 L T1 - T0
    } else {
      lapply_col<1>(sLgT, sT1, sH, sT2, rcol);
    }
    __syncthreads();  // B3: T2 complete

    if (isTile) {
      mm4x4_acc<64>(acc, sT2, LDH, i4, sWB + 2 * 65 * 64, 64, j4);
      mm_tail65(acc, sT2, i4, sWB + 2 * 65 * 64, j4);
      lapply_tile<1>(sLg, sT2, sT1, sT1, i4, j4);  // T3 = 2 L T2 - T1 (in place)
    } else {
      lapply_col<1>(sLgT, sT2, sT1, sT1, rcol);
    }
    __syncthreads();  // B4: T3 complete

    if (isTile) {
      mm4x4_acc<64>(acc, sT1, LDH, i4, sWB + 3 * 65 * 64, 64, j4);
      mm_tail65(acc, sT1, i4, sWB + 3 * 65 * 64, j4);
      // h_new = sigmoid(acc)
#pragma unroll
      for (int rr = 0; rr < 4; ++rr) {
        float4 o;
        o.x = 1.f / (1.f + expf(-acc[rr][0]));
        o.y = 1.f / (1.f + expf(-acc[rr][1]));
        o.z = 1.f / (1.f + expf(-acc[rr][2]));
        o.w = 1.f / (1.f + expf(-acc[rr][3]));
        *(float4*)(sH + (i4 + rr) * LDH + j4) = o;
      }
    }
    __syncthreads();  // B5: h updated
  }

  // ---------- Phase 3: two GCN layers + FC + log_softmax ----------
  // rebuild dense GCN matrix (incl. self-loop diag) into sLg
  for (int idx = tid; idx < NODES * LDH; idx += NTHREADS) sLg[idx] = 0.f;
  if (tid < NODES) sDeg[tid] = 0.f;
  __syncthreads();
  for (int e = tid; e < EPG; e += NTHREADS) {
    const int dl = edst[ebase + e] - gbase;
    atomicAdd(&sDeg[dl], ew[ebase + e]);
  }
  __syncthreads();
  if (tid < NODES) sDinv[tid] = 1.f / sqrtf(sDeg[tid] + 1.f);
  __syncthreads();
  for (int e = tid; e < EPG; e += NTHREADS) {
    const int sl = esrc[ebase + e] - gbase;
    const int dl = edst[ebase + e] - gbase;
    const float nrm = sDinv[sl] * ew[ebase + e] * sDinv[dl];
    atomicAdd(&sLg[dl * LDH + sl], nrm);
  }
  // stage w1 / w2 / b1 / b2 into sWB space (no longer needed for cheb)
  for (int idx = tid; idx < 4096; idx += NTHREADS) sWB[idx] = w1[idx];
  for (int idx = tid; idx < 2048; idx += NTHREADS) sWB[4096 + idx] = w2[idx];
  if (tid < 64) sWB[6144 + tid] = b1[tid];
  if (tid < 32) sWB[6208 + tid] = b2[tid];
  if (tid < 4) sLogit[tid] = bfc[tid];
  __syncthreads();
  if (tid < NODES) sLg[tid * LDH + tid] += sDinv[tid] * sDinv[tid];
  __syncthreads();

  // xw1 = h @ w1  -> sT2
  if (isTile) {
    float m[4][4] = {};
    mm4x4_acc<64>(m, sH, LDH, i4, sWB, 64, j4);
#pragma unroll
    for (int rr = 0; rr < 4; ++rr) {
      float4 o = make_float4(m[rr][0], m[rr][1], m[rr][2], m[rr][3]);
      *(float4*)(sT2 + (i4 + rr) * LDH + j4) = o;
    }
  }
  __syncthreads();
  // z1 = relu(Ag @ xw1 + b1) -> sT1
  if (isTile) {
    float m[4][4] = {};
    mm4x4_acc<64>(m, sLg, LDH, i4, sT2, LDH, j4);
#pragma unroll
    for (int rr = 0; rr < 4; ++rr) {
      float4 o;
      o.x = fmaxf(m[rr][0] + sWB[6144 + j4 + 0], 0.f);
      o.y = fmaxf(m[rr][1] + sWB[6144 + j4 + 1], 0.f);
      o.z = fmaxf(m[rr][2] + sWB[6144 + j4 + 2], 0.f);
      o.w = fmaxf(m[rr][3] + sWB[6144 + j4 + 3], 0.f);
      *(float4*)(sT1 + (i4 + rr) * LDH + j4) = o;
    }
  }
  __syncthreads();
  // xw2 = z1 @ w2 -> sT2 (cols 0..31)
  if (isTile && j4 < 32) {
    float m[4][4] = {};
    mm4x4_acc<64>(m, sT1, LDH, i4, sWB + 4096, 32, j4);
#pragma unroll
    for (int rr = 0; rr < 4; ++rr) {
      float4 o = make_float4(m[rr][0], m[rr][1], m[rr][2], m[rr][3]);
      *(float4*)(sT2 + (i4 + rr) * LDH + j4) = o;
    }
  }
  __syncthreads();
  // z2 = relu(Ag @ xw2 + b2) -> sT1 (cols 0..31)
  if (isTile && j4 < 32) {
    float m[4][4] = {};
    mm4x4_acc<64>(m, sLg, LDH, i4, sT2, LDH, j4);
#pragma unroll
    for (int rr = 0; rr < 4; ++rr) {
      float4 o;
      o.x = fmaxf(m[rr][0] + sWB[6208 + j4 + 0], 0.f);
      o.y = fmaxf(m[rr][1] + sWB[6208 + j4 + 1], 0.f);
      o.z = fmaxf(m[rr][2] + sWB[6208 + j4 + 2], 0.f);
      o.w = fmaxf(m[rr][3] + sWB[6208 + j4 + 3], 0.f);
      *(float4*)(sT1 + (i4 + rr) * LDH + j4) = o;
    }
  }
  __syncthreads();

  // FC: logits[cl] = sum_{n,c} z2[n][c] * wfc[(n*32+c)*4 + cl] + bfc[cl]
  float p0 = 0.f, p1 = 0.f, p2 = 0.f, p3 = 0.f;
  for (int f = tid; f < 2048; f += NTHREADS) {
    const int n = f >> 5;
    const int c = f & 31;
    const float v = sT1[n * LDH + c];
    const float4 wv = *(const float4*)(wfc + f * 4);
    p0 += v * wv.x; p1 += v * wv.y; p2 += v * wv.z; p3 += v * wv.w;
  }
#pragma unroll
  for (int off = 1; off < 64; off <<= 1) {
    p0 += __shfl_xor(p0, off);
    p1 += __shfl_xor(p1, off);
    p2 += __shfl_xor(p2, off);
    p3 += __shfl_xor(p3, off);
  }
  if ((tid & 63) == 0) {
    atomicAdd(&sLogit[0], p0);
    atomicAdd(&sLogit[1], p1);
    atomicAdd(&sLogit[2], p2);
    atomicAdd(&sLogit[3], p3);
  }
  __syncthreads();
  if (tid == 0) {
    const float l0 = sLogit[0], l1 = sLogit[1], l2 = sLogit[2], l3 = sLogit[3];
    const float mx = fmaxf(fmaxf(l0, l1), fmaxf(l2, l3));
    const float s = expf(l0 - mx) + expf(l1 - mx) + expf(l2 - mx) + expf(l3 - mx);
    const float lse = mx + logf(s);
    out[b * 4 + 0] = l0 - lse;
    out[b * 4 + 1] = l1 - lse;
    out[b * 4 + 2] = l2 - lse;
    out[b * 4 + 3] = l3 - lse;
  }
}

extern "C" void kernel_launch(void* const* d_in, const int* in_sizes, int n_in,
                              void* d_out, int out_size, void* d_ws, size_t ws_size,
                              hipStream_t stream) {
  gcrnn_gcn_fused<<<NBLOCKS, NTHREADS, 0, stream>>>(
      (const float*)d_in[0],   // x
      (const float*)d_in[1],   // edge_weight
      (const float*)d_in[2],   // wA
      (const float*)d_in[3],   // bA
      (const float*)d_in[4],   // wB
      (const float*)d_in[5],   // bB
      (const float*)d_in[6],   // w1
      (const float*)d_in[7],   // b1
      (const float*)d_in[8],   // w2
      (const float*)d_in[9],   // b2
      (const float*)d_in[10],  // wfc
      (const float*)d_in[11],  // bfc
      (const int*)d_in[12],    // edge_src
      (const int*)d_in[13],    // edge_dst
      (float*)d_out);
}

// Round 2
// 254.800 us; speedup vs baseline: 3.9636x; 3.9636x over previous
//
#include <hip/hip_runtime.h>
#include <math.h>

#define NODES 64
#define NSTEPS 64
#define EPG 1024
#define NTHREADS 320
#define NBLOCKS 256
#define LDT 72      // fp16 row stride for T / L arrays
#define LDW 296     // fp16 row stride for Wt (K=296 padded)
#define LDH 68      // fp32 stride for phase-3 arrays

typedef _Float16 f16;
typedef f16 f16x8 __attribute__((ext_vector_type(8)));
typedef f16 f16x4 __attribute__((ext_vector_type(4)));
typedef float f32x4 __attribute__((ext_vector_type(4)));

// ---- LDS layout (byte offsets into one char array) ----
#define OFF_L2R   0        // f16 [64][72]  : 2*L (scaled Laplacian row-major)
#define OFF_TT0   9216     // f16 [64][72]  : T0^T = h^T  [feat][node]
#define OFF_TT1   18432
#define OFF_TT2   27648
#define OFF_TR0A  36864    // f16 [64][72]  : T0 = h  [node][feat]  (double-buffered)
#define OFF_TR0B  46080
#define OFF_TR1   55296
#define OFF_TR2   64512
#define OFF_TR3   73728
#define OFF_WT    82944    // f16 [64][296] : Wcat^T  [outchan][kcat], 37888 B
#define OFF_XT    120832   // f32 [64][64]  : x transposed [t][node]
#define OFF_LGF   137216   // f32 [64][64]  : phase-1 fp32 Laplacian scratch
#define OFF_TXA   153600   // f16 [64][8]   : x-path cheb values t0..t3 (+4 zero)
#define OFF_BSUM  154624
#define OFF_DEG   154880
#define OFF_DINV  155136
#define OFF_LOGIT 155392
#define SMEM_BYTES 155648

__device__ __forceinline__ f32x4 mfma16(f16x8 a, f16x8 b, f32x4 c) {
  return __builtin_amdgcn_mfma_f32_16x16x32_f16(a, b, c, 0, 0, 0);
}

// write D tiles (2x2 quadrant, 16x16 each) to Tt (transposed, b64) and/or Tr (row-major, b16 scatter)
__device__ __forceinline__ void storeT(f16* __restrict__ Tt, f16* __restrict__ Tr,
                                       const f32x4 (&D)[2][2], int wr, int wc,
                                       int lrow, int lk, bool doTt, bool doTr)
{
#pragma unroll
  for (int tr = 0; tr < 2; ++tr)
#pragma unroll
    for (int tc = 0; tc < 2; ++tc) {
      const int Rb = wr * 32 + tr * 16 + lk * 4;    // node-row base of this lane's 4 values
      const int Cb = wc * 32 + tc * 16 + lrow;      // feat-col of this lane
      const f32x4 v = D[tr][tc];
      if (doTt) {
        f16x4 w;
        w[0] = (f16)v[0]; w[1] = (f16)v[1]; w[2] = (f16)v[2]; w[3] = (f16)v[3];
        *(f16x4*)(Tt + Cb * LDT + Rb) = w;
      }
      if (doTr) {
#pragma unroll
        for (int r = 0; r < 4; ++r) Tr[(Rb + r) * LDT + Cb] = (f16)v[r];
      }
    }
}

// col-wave: acc = sum_k (2L)[n][k] * t[k], t distributed one value per lane
__device__ __forceinline__ float dotL2(const f16x8* lr, float tv) {
  const int ti = __builtin_bit_cast(int, tv);
  float acc = 0.f;
#pragma unroll
  for (int c = 0; c < 8; ++c) {
#pragma unroll
    for (int j = 0; j < 8; ++j) {
      const float t = __builtin_bit_cast(float, __builtin_amdgcn_readlane(ti, c * 8 + j));
      acc += (float)lr[c][j] * t;
    }
  }
  return acc;
}

// fp32 4x4-tile matmul helper for phase 3 (unchanged from R1)
template<int K>
__device__ __forceinline__ void mm4x4_acc(float acc[4][4],
                                          const float* __restrict__ A, int lda, int arow,
                                          const float* __restrict__ Bm, int ldb, int j4)
{
#pragma unroll 2
  for (int kc = 0; kc < K; kc += 4) {
    float av[4][4];
    float bv[4][4];
#pragma unroll
    for (int rr = 0; rr < 4; ++rr) {
      const float4 t = *(const float4*)(A + (arow + rr) * lda + kc);
      av[rr][0] = t.x; av[rr][1] = t.y; av[rr][2] = t.z; av[rr][3] = t.w;
    }
#pragma unroll
    for (int kk = 0; kk < 4; ++kk) {
      const float4 t = *(const float4*)(Bm + (kc + kk) * ldb + j4);
      bv[kk][0] = t.x; bv[kk][1] = t.y; bv[kk][2] = t.z; bv[kk][3] = t.w;
    }
#pragma unroll
    for (int rr = 0; rr < 4; ++rr)
#pragma unroll
      for (int cc = 0; cc < 4; ++cc) {
        float s = acc[rr][cc];
#pragma unroll
        for (int kk = 0; kk < 4; ++kk) s += av[rr][kk] * bv[kk][cc];
        acc[rr][cc] = s;
      }
  }
}

__global__ __launch_bounds__(NTHREADS, 1)
void gcrnn_gcn_mfma(const float* __restrict__ x,     // [16384][64]
                    const float* __restrict__ ew,    // [262144]
                    const float* __restrict__ wA,    // [4][1][64]
                    const float* __restrict__ bA,    // [64]
                    const float* __restrict__ wB,    // [4][64][64]
                    const float* __restrict__ bB,    // [64]
                    const float* __restrict__ w1,    // [64][64]
                    const float* __restrict__ b1,    // [64]
                    const float* __restrict__ w2,    // [64][32]
                    const float* __restrict__ b2,    // [32]
                    const float* __restrict__ wfc,   // [2048][4]
                    const float* __restrict__ bfc,   // [4]
                    const int* __restrict__ esrc,
                    const int* __restrict__ edst,
                    float* __restrict__ out)         // [256][4]
{
  __shared__ __align__(16) char smem[SMEM_BYTES];

  f16*   sL2r  = (f16*)(smem + OFF_L2R);
  f16*   sTt0  = (f16*)(smem + OFF_TT0);
  f16*   sTt1  = (f16*)(smem + OFF_TT1);
  f16*   sTt2  = (f16*)(smem + OFF_TT2);
  f16*   sTr0a = (f16*)(smem + OFF_TR0A);
  f16*   sTr0b = (f16*)(smem + OFF_TR0B);
  f16*   sTr1  = (f16*)(smem + OFF_TR1);
  f16*   sTr2  = (f16*)(smem + OFF_TR2);
  f16*   sTr3  = (f16*)(smem + OFF_TR3);
  f16*   sWt   = (f16*)(smem + OFF_WT);
  float* sXT   = (float*)(smem + OFF_XT);
  float* sLgF  = (float*)(smem + OFF_LGF);
  f16*   sTxA  = (f16*)(smem + OFF_TXA);
  float* sBsum = (float*)(smem + OFF_BSUM);
  float* sDeg  = (float*)(smem + OFF_DEG);
  float* sDinv = (float*)(smem + OFF_DINV);
  float* sLogit= (float*)(smem + OFF_LOGIT);

  const int b     = blockIdx.x;
  const int tid   = threadIdx.x;
  const int gbase = b * NODES;
  const int ebase = b * EPG;

  const int  wid    = tid >> 6;
  const int  lane   = tid & 63;
  const bool isMfma = wid < 4;
  const int  wr     = (wid >> 1) & 1;
  const int  wc     = wid & 1;
  const int  lrow   = lane & 15;
  const int  lk     = lane >> 4;

  // ---------------- Phase 0: zero + stage ----------------
  // zero all T buffers (Tt0..Tr3): bytes OFF_TT0 .. OFF_WT
  for (int idx = tid; idx < (OFF_WT - OFF_TT0) / 4; idx += NTHREADS)
    ((int*)(smem + OFF_TT0))[idx] = 0;
  for (int idx = tid; idx < 256; idx += NTHREADS)   // TxA
    ((int*)(smem + OFF_TXA))[idx] = 0;
  for (int idx = tid; idx < 4096; idx += NTHREADS)  // LgF
    sLgF[idx] = 0.f;
  if (tid < 64) { sDeg[tid] = 0.f; sBsum[tid] = bA[tid] + bB[tid]; }

  // stage Wcat^T : sWt[c][k], k 0..255 = wB, 256..259 = wA, 260..295 = 0
  for (int idx = tid; idx < 64 * LDW; idx += NTHREADS) {
    const int c = idx / LDW;
    const int k = idx - c * LDW;
    float v = 0.f;
    if (k < 256)      v = wB[((k >> 6) * 64 + (k & 63)) * 64 + c];
    else if (k < 260) v = wA[(k - 256) * 64 + c];
    sWt[c * LDW + k] = (f16)v;
  }
  // stage x transposed: sXT[t][n] = x[gbase+n][t]
  for (int idx = tid; idx < 4096; idx += NTHREADS) {
    const int n = idx >> 6, c = idx & 63;
    sXT[c * 64 + n] = x[(gbase + n) * 64 + c];
  }
  __syncthreads();

  // ---------------- Phase 1: dense Laplacian ----------------
  for (int e = tid; e < EPG; e += NTHREADS) {
    const int sl = esrc[ebase + e] - gbase;
    atomicAdd(&sDeg[sl], ew[ebase + e]);
  }
  __syncthreads();
  if (tid < 64) {
    const float d = sDeg[tid];
    sDinv[tid] = (d > 0.f) ? rsqrtf(d) : 0.f;
  }
  __syncthreads();
  for (int e = tid; e < EPG; e += NTHREADS) {
    const int sl = esrc[ebase + e] - gbase;
    const int dl = edst[ebase + e] - gbase;
    atomicAdd(&sLgF[dl * 64 + sl], -(sDinv[sl] * ew[ebase + e] * sDinv[dl]));
  }
  __syncthreads();
  // convert to fp16 2*L with padded stride
  for (int idx = tid; idx < 64 * LDT; idx += NTHREADS) {
    const int n = idx / LDT;
    const int k = idx - n * LDT;
    sL2r[idx] = (k < 64) ? (f16)(2.f * sLgF[n * 64 + k]) : (f16)0.f;
  }
  __syncthreads();

  // ---------------- register preload (constant across scan) ----------------
  f16x8 lfrag[2][2];   // MFMA waves: 2L A-frags [tr][ch]
  f16x8 lrr[8];        // col wave: own row of 2L
  if (isMfma) {
#pragma unroll
    for (int tr = 0; tr < 2; ++tr)
#pragma unroll
      for (int ch = 0; ch < 2; ++ch)
        lfrag[tr][ch] = *(const f16x8*)(sL2r + (wr * 32 + tr * 16 + lrow) * LDT + ch * 32 + lk * 8);
  } else {
#pragma unroll
    for (int c = 0; c < 8; ++c)
      lrr[c] = *(const f16x8*)(sL2r + lane * LDT + c * 8);
  }

  f32x4 hD[2][2];      // persistent: T0 = h, fp32 D-layout
#pragma unroll
  for (int tr = 0; tr < 2; ++tr)
#pragma unroll
    for (int tc = 0; tc < 2; ++tc) hD[tr][tc] = (f32x4){0.f, 0.f, 0.f, 0.f};

  // ---------------- Phase 2: T=64 scan ----------------
#pragma unroll 1
  for (int t = 0; t < NSTEPS; ++t) {
    f32x4 t1D[2][2];
    // ---- M1: T1 = 0.5 * (2L @ T0);  col wave: x-path cheb ----
    if (isMfma) {
      f32x4 d[2][2];
#pragma unroll
      for (int tr = 0; tr < 2; ++tr)
#pragma unroll
        for (int tc = 0; tc < 2; ++tc) d[tr][tc] = (f32x4){0.f, 0.f, 0.f, 0.f};
#pragma unroll
      for (int ch = 0; ch < 2; ++ch) {
        f16x8 b0 = *(const f16x8*)(sTt0 + (wc * 32 +  0 + lrow) * LDT + ch * 32 + lk * 8);
        f16x8 b1 = *(const f16x8*)(sTt0 + (wc * 32 + 16 + lrow) * LDT + ch * 32 + lk * 8);
        d[0][0] = mfma16(lfrag[0][ch], b0, d[0][0]);
        d[0][1] = mfma16(lfrag[0][ch], b1, d[0][1]);
        d[1][0] = mfma16(lfrag[1][ch], b0, d[1][0]);
        d[1][1] = mfma16(lfrag[1][ch], b1, d[1][1]);
      }
#pragma unroll
      for (int tr = 0; tr < 2; ++tr)
#pragma unroll
        for (int tc = 0; tc < 2; ++tc) t1D[tr][tc] = d[tr][tc] * 0.5f;
      storeT(sTt1, sTr1, t1D, wr, wc, lrow, lk, true, true);
    } else {
      const int n = lane;
      const float tx0 = sXT[t * 64 + n];
      const float tx1 = 0.5f * dotL2(lrr, tx0);
      const float tx2 = dotL2(lrr, tx1) - tx0;
      const float tx3 = dotL2(lrr, tx2) - tx1;
      f16x4 w;
      w[0] = (f16)tx0; w[1] = (f16)tx1; w[2] = (f16)tx2; w[3] = (f16)tx3;
      *(f16x4*)(sTxA + n * 8) = w;
    }
    __syncthreads();  // b1

    // ---- M2: T2 = 2L @ T1 - T0  (C-init = -hD from registers) ----
    f32x4 t2D[2][2];
    if (isMfma) {
#pragma unroll
      for (int tr = 0; tr < 2; ++tr)
#pragma unroll
        for (int tc = 0; tc < 2; ++tc) t2D[tr][tc] = -hD[tr][tc];
#pragma unroll
      for (int ch = 0; ch < 2; ++ch) {
        f16x8 b0 = *(const f16x8*)(sTt1 + (wc * 32 +  0 + lrow) * LDT + ch * 32 + lk * 8);
        f16x8 b1 = *(const f16x8*)(sTt1 + (wc * 32 + 16 + lrow) * LDT + ch * 32 + lk * 8);
        t2D[0][0] = mfma16(lfrag[0][ch], b0, t2D[0][0]);
        t2D[0][1] = mfma16(lfrag[0][ch], b1, t2D[0][1]);
        t2D[1][0] = mfma16(lfrag[1][ch], b0, t2D[1][0]);
        t2D[1][1] = mfma16(lfrag[1][ch], b1, t2D[1][1]);
      }
      storeT(sTt2, sTr2, t2D, wr, wc, lrow, lk, true, true);
    }
    __syncthreads();  // b2

    // ---- M3: T3 = 2L @ T2 - T1  (C-init = -t1D) ----
    if (isMfma) {
      f32x4 d[2][2];
#pragma unroll
      for (int tr = 0; tr < 2; ++tr)
#pragma unroll
        for (int tc = 0; tc < 2; ++tc) d[tr][tc] = -t1D[tr][tc];
#pragma unroll
      for (int ch = 0; ch < 2; ++ch) {
        f16x8 b0 = *(const f16x8*)(sTt2 + (wc * 32 +  0 + lrow) * LDT + ch * 32 + lk * 8);
        f16x8 b1 = *(const f16x8*)(sTt2 + (wc * 32 + 16 + lrow) * LDT + ch * 32 + lk * 8);
        d[0][0] = mfma16(lfrag[0][ch], b0, d[0][0]);
        d[0][1] = mfma16(lfrag[0][ch], b1, d[0][1]);
        d[1][0] = mfma16(lfrag[1][ch], b0, d[1][0]);
        d[1][1] = mfma16(lfrag[1][ch], b1, d[1][1]);
      }
      storeT(sTt2 /*unused*/, sTr3, d, wr, wc, lrow, lk, false, true);
    }
    __syncthreads();  // b3  (TxA also guaranteed written)

    // ---- M4: pre = bsum + [T0|T1|T2|T3|tx] @ Wcat ; h = sigmoid(pre) ----
    if (isMfma) {
      f32x4 p[2][2];
#pragma unroll
      for (int tc = 0; tc < 2; ++tc) {
        const float bs = sBsum[wc * 32 + tc * 16 + lrow];
        p[0][tc] = (f32x4){bs, bs, bs, bs};
        p[1][tc] = (f32x4){bs, bs, bs, bs};
      }
      const f16* trRd = (t & 1) ? sTr0b : sTr0a;
      const f16* asrc[4] = { trRd, sTr1, sTr2, sTr3 };
#pragma unroll
      for (int ch = 0; ch < 8; ++ch) {
        const f16* As = asrc[ch >> 1];
        const int  ko = (ch & 1) * 32 + lk * 8;
        f16x8 a0 = *(const f16x8*)(As + (wr * 32 +  0 + lrow) * LDT + ko);
        f16x8 a1 = *(const f16x8*)(As + (wr * 32 + 16 + lrow) * LDT + ko);
        f16x8 b0 = *(const f16x8*)(sWt + (wc * 32 +  0 + lrow) * LDW + ch * 32 + lk * 8);
        f16x8 b1 = *(const f16x8*)(sWt + (wc * 32 + 16 + lrow) * LDW + ch * 32 + lk * 8);
        p[0][0] = mfma16(a0, b0, p[0][0]);
        p[0][1] = mfma16(a0, b1, p[0][1]);
        p[1][0] = mfma16(a1, b0, p[1][0]);
        p[1][1] = mfma16(a1, b1, p[1][1]);
      }
      { // chunk 8: x-path columns (k 256..259 real, 260..295 zero in Wt)
        f16x8 zz;
#pragma unroll
        for (int j = 0; j < 8; ++j) zz[j] = (f16)0.f;
        f16x8 a0 = *(const f16x8*)(sTxA + (wr * 32 +  0 + lrow) * 8);
        f16x8 a1 = *(const f16x8*)(sTxA + (wr * 32 + 16 + lrow) * 8);
        if (lk != 0) { a0 = zz; a1 = zz; }
        f16x8 b0 = *(const f16x8*)(sWt + (wc * 32 +  0 + lrow) * LDW + 256 + lk * 8);
        f16x8 b1 = *(const f16x8*)(sWt + (wc * 32 + 16 + lrow) * LDW + 256 + lk * 8);
        p[0][0] = mfma16(a0, b0, p[0][0]);
        p[0][1] = mfma16(a0, b1, p[0][1]);
        p[1][0] = mfma16(a1, b0, p[1][0]);
        p[1][1] = mfma16(a1, b1, p[1][1]);
      }
      // sigmoid -> new h (registers) + store both layouts
#pragma unroll
      for (int tr = 0; tr < 2; ++tr)
#pragma unroll
        for (int tc = 0; tc < 2; ++tc)
#pragma unroll
          for (int r = 0; r < 4; ++r)
            hD[tr][tc][r] = 1.f / (1.f + __expf(-p[tr][tc][r]));
      f16* trWr = (t & 1) ? sTr0a : sTr0b;
      storeT(sTt0, trWr, hD, wr, wc, lrow, lk, true, true);
    }
    __syncthreads();  // b4
  }

  // ---------------- Phase 3: GCN x2 + FC + log_softmax (fp32) ----------------
  float* sW   = (float*)smem;                       // 6272 floats
  float* sLgG = (float*)(smem + OFF_WT);            // [64][68]
  float* sT1g = (float*)(smem + OFF_WT + 17408);    // [64][68]
  float* sT2g = (float*)(smem + OFF_XT);            // [64][68]
  const f16* hSrc = (const f16*)(smem + OFF_TR0A);  // final h (t=63 writes buffer A)

  for (int idx = tid; idx < 64 * LDH; idx += NTHREADS) sLgG[idx] = 0.f;
  if (tid < 64) sDeg[tid] = 0.f;
  for (int idx = tid; idx < 4096; idx += NTHREADS) {
    const int n = idx >> 6, c = idx & 63;
    sT1g[n * LDH + c] = (float)hSrc[n * LDT + c];
  }
  for (int idx = tid; idx < 4096; idx += NTHREADS) sW[idx] = w1[idx];
  for (int idx = tid; idx < 2048; idx += NTHREADS) sW[4096 + idx] = w2[idx];
  if (tid < 64) sW[6144 + tid] = b1[tid];
  if (tid < 32) sW[6208 + tid] = b2[tid];
  if (tid < 4)  sLogit[tid] = bfc[tid];
  __syncthreads();

  for (int e = tid; e < EPG; e += NTHREADS)
    atomicAdd(&sDeg[edst[ebase + e] - gbase], ew[ebase + e]);
  __syncthreads();
  if (tid < 64) sDinv[tid] = rsqrtf(sDeg[tid] + 1.f);
  __syncthreads();
  for (int e = tid; e < EPG; e += NTHREADS) {
    const int sl = esrc[ebase + e] - gbase;
    const int dl = edst[ebase + e] - gbase;
    atomicAdd(&sLgG[dl * LDH + sl], sDinv[sl] * ew[ebase + e] * sDinv[dl]);
  }
  __syncthreads();
  if (tid < 64) sLgG[tid * LDH + tid] += sDinv[tid] * sDinv[tid];
  __syncthreads();

  const bool isTile = tid < 256;
  const int  i4 = ((tid >> 4) & 15) * 4;
  const int  j4 = (tid & 15) * 4;

  // xw1 = h @ w1 -> sT2g
  if (isTile) {
    float m[4][4] = {};
    mm4x4_acc<64>(m, sT1g, LDH, i4, sW, 64, j4);
#pragma unroll
    for (int rr = 0; rr < 4; ++rr)
      *(float4*)(sT2g + (i4 + rr) * LDH + j4) = make_float4(m[rr][0], m[rr][1], m[rr][2], m[rr][3]);
  }
  __syncthreads();
  // z1 = relu(Ag @ xw1 + b1) -> sT1g
  if (isTile) {
    float m[4][4] = {};
    mm4x4_acc<64>(m, sLgG, LDH, i4, sT2g, LDH, j4);
#pragma unroll
    for (int rr = 0; rr < 4; ++rr) {
      float4 o;
      o.x = fmaxf(m[rr][0] + sW[6144 + j4 + 0], 0.f);
      o.y = fmaxf(m[rr][1] + sW[6144 + j4 + 1], 0.f);
      o.z = fmaxf(m[rr][2] + sW[6144 + j4 + 2], 0.f);
      o.w = fmaxf(m[rr][3] + sW[6144 + j4 + 3], 0.f);
      *(float4*)(sT1g + (i4 + rr) * LDH + j4) = o;
    }
  }
  __syncthreads();
  // xw2 = z1 @ w2 -> sT2g (cols 0..31)
  if (isTile && j4 < 32) {
    float m[4][4] = {};
    mm4x4_acc<64>(m, sT1g, LDH, i4, sW + 4096, 32, j4);
#pragma unroll
    for (int rr = 0; rr < 4; ++rr)
      *(float4*)(sT2g + (i4 + rr) * LDH + j4) = make_float4(m[rr][0], m[rr][1], m[rr][2], m[rr][3]);
  }
  __syncthreads();
  // z2 = relu(Ag @ xw2 + b2) -> sT1g (cols 0..31)
  if (isTile && j4 < 32) {
    float m[4][4] = {};
    mm4x4_acc<64>(m, sLgG, LDH, i4, sT2g, LDH, j4);
#pragma unroll
    for (int rr = 0; rr < 4; ++rr) {
      float4 o;
      o.x = fmaxf(m[rr][0] + sW[6208 + j4 + 0], 0.f);
      o.y = fmaxf(m[rr][1] + sW[6208 + j4 + 1], 0.f);
      o.z = fmaxf(m[rr][2] + sW[6208 + j4 + 2], 0.f);
      o.w = fmaxf(m[rr][3] + sW[6208 + j4 + 3], 0.f);
      *(float4*)(sT1g + (i4 + rr) * LDH + j4) = o;
    }
  }
  __syncthreads();

  // FC + log_softmax
  float p0 = 0.f, p1 = 0.f, p2 = 0.f, p3 = 0.f;
  for (int f = tid; f < 2048; f += NTHREADS) {
    const int n = f >> 5;
    const int c = f & 31;
    const float v = sT1g[n * LDH + c];
    const float4 wv = *(const float4*)(wfc + f * 4);
    p0 += v * wv.x; p1 += v * wv.y; p2 += v * wv.z; p3 += v * wv.w;
  }
#pragma unroll
  for (int off = 1; off < 64; off <<= 1) {
    p0 += __shfl_xor(p0, off);
    p1 += __shfl_xor(p1, off);
    p2 += __shfl_xor(p2, off);
    p3 += __shfl_xor(p3, off);
  }
  if ((tid & 63) == 0) {
    atomicAdd(&sLogit[0], p0);
    atomicAdd(&sLogit[1], p1);
    atomicAdd(&sLogit[2], p2);
    atomicAdd(&sLogit[3], p3);
  }
  __syncthreads();
  if (tid == 0) {
    const float l0 = sLogit[0], l1 = sLogit[1], l2 = sLogit[2], l3 = sLogit[3];
    const float mx = fmaxf(fmaxf(l0, l1), fmaxf(l2, l3));
    const float s = expf(l0 - mx) + expf(l1 - mx) + expf(l2 - mx) + expf(l3 - mx);
    const float lse = mx + logf(s);
    out[b * 4 + 0] = l0 - lse;
    out[b * 4 + 1] = l1 - lse;
    out[b * 4 + 2] = l2 - lse;
    out[b * 4 + 3] = l3 - lse;
  }
}

extern "C" void kernel_launch(void* const* d_in, const int* in_sizes, int n_in,
                              void* d_out, int out_size, void* d_ws, size_t ws_size,
                              hipStream_t stream) {
  gcrnn_gcn_mfma<<<NBLOCKS, NTHREADS, 0, stream>>>(
      (const float*)d_in[0],   // x
      (const float*)d_in[1],   // edge_weight
      (const float*)d_in[2],   // wA
      (const float*)d_in[3],   // bA
      (const float*)d_in[4],   // wB
      (const float*)d_in[5],   // bB
      (const float*)d_in[6],   // w1
      (const float*)d_in[7],   // b1
      (const float*)d_in[8],   // w2
      (const float*)d_in[9],   // b2
      (const float*)d_in[10],  // wfc
      (const float*)d_in[11],  // bfc
      (const int*)d_in[12],    // edge_src
      (const int*)d_in[13],    // edge_dst
      (float*)d_out);
}

// Round 3
// 107.149 us; speedup vs baseline: 9.4255x; 2.3780x over previous
//
#include <hip/hip_runtime.h>
#include <math.h>

#define NODES 64
#define NSTEPS 64
#define EPG 1024
#define NTHREADS 512
#define NBLOCKS 256

typedef _Float16 f16;
typedef f16 f16x8 __attribute__((ext_vector_type(8)));
typedef f16 f16x4 __attribute__((ext_vector_type(4)));
typedef float f32x4 __attribute__((ext_vector_type(4)));

// ---- LDS layout (byte offsets). [64][72] f16 = 9216 B unless noted ----
#define OFF_M1    0        // M1=Lambda row-major      -> scan: Y1
#define OFF_M2    9216     // M2 row-major             -> scan: Y2
#define OFF_M3    18432    // M3 row-major             -> scan: Y3
#define OFF_M1T   27648    // Lambda^T                 -> scan: h buf A
#define OFF_M2T   36864    // M2^T                     -> scan: h buf B
#define OFF_TT    46080    // h^T [feat][node]
#define OFF_ZALL  55296    // f16 [4][64 t][72 n] = 36864  (k=0 doubles as X^T staging)
#define OFF_WT    92160    // f16 [64 c][304 K] = 38912
#define OFF_ZST   131072   // f16 [64 n][40] = 5120 (z_t chunk, cols 4..39 zero)
#define OFF_LGF   136192   // f32 [64][64] = 16384 (Laplacian scratch)
#define OFF_DEG   152576
#define OFF_DINV  152832
#define OFF_BSUM  153088
#define OFF_LOGIT 153344
#define SMEM_BYTES 153600

__device__ __forceinline__ f32x4 mfma16(f16x8 a, f16x8 b, f32x4 c) {
  return __builtin_amdgcn_mfma_f32_16x16x32_f16(a, b, c, 0, 0, 0);
}

// one 64x64 (K=64) matmul; wave computes tiles (rb,cb0),(rb,cb0+1).
// A rows read by lrow (row space), B rows read by lrow (col space); stride 72.
__device__ __forceinline__ void mm64(const f16* __restrict__ A, const f16* __restrict__ B,
                                     int rb, int cb0, int lrow, int lk,
                                     f32x4& d0, f32x4& d1)
{
  d0 = (f32x4){0.f, 0.f, 0.f, 0.f};
  d1 = d0;
#pragma unroll
  for (int ch = 0; ch < 2; ++ch) {
    const f16x8 a  = *(const f16x8*)(A + (rb * 16 + lrow) * 72 + ch * 32 + lk * 8);
    const f16x8 b0 = *(const f16x8*)(B + (cb0 * 16 + lrow) * 72 + ch * 32 + lk * 8);
    const f16x8 b1 = *(const f16x8*)(B + (cb0 * 16 + 16 + lrow) * 72 + ch * 32 + lk * 8);
    d0 = mfma16(a, b0, d0);
    d1 = mfma16(a, b1, d1);
  }
}

// store helpers: D[p][q] computed with p=row-space, q=col-space; write dst[q][p] (transposed => f16x4)
__device__ __forceinline__ void stM2s(f16* dst, const f32x4& d, int rb, int cb, int lrow, int lk) {
  const int p0 = rb * 16 + lk * 4, q = cb * 16 + lrow;
  f16x4 w;
#pragma unroll
  for (int r = 0; r < 4; ++r) w[r] = (f16)(2.f * d[r] - ((p0 + r) == q ? 1.f : 0.f));
  *(f16x4*)(dst + q * 72 + p0) = w;
}
__device__ __forceinline__ void stM3s(f16* dst, const f16* lam, const f32x4& d, int rb, int cb, int lrow, int lk) {
  const int p0 = rb * 16 + lk * 4, q = cb * 16 + lrow;
  const f16x4 lv = *(const f16x4*)(lam + q * 72 + p0);
  f16x4 w;
#pragma unroll
  for (int r = 0; r < 4; ++r) w[r] = (f16)(2.f * d[r] - (float)lv[r]);
  *(f16x4*)(dst + q * 72 + p0) = w;
}
__device__ __forceinline__ void stZs(f16* dst, const f32x4& d, int rb, int cb, int lrow, int lk) {
  const int p0 = rb * 16 + lk * 4, q = cb * 16 + lrow;   // q = t, p = node
  f16x4 w;
#pragma unroll
  for (int r = 0; r < 4; ++r) w[r] = (f16)d[r];
  *(f16x4*)(dst + q * 72 + p0) = w;
}

// fp32 4x4-tile matmul (phase 3); Bm may be a GLOBAL pointer (L1/L2 cached)
template<int K>
__device__ __forceinline__ void mm4x4_acc(float acc[4][4],
                                          const float* __restrict__ A, int lda, int arow,
                                          const float* __restrict__ Bm, int ldb, int j4)
{
#pragma unroll 2
  for (int kc = 0; kc < K; kc += 4) {
    float av[4][4];
    float bv[4][4];
#pragma unroll
    for (int rr = 0; rr < 4; ++rr) {
      const float4 t = *(const float4*)(A + (arow + rr) * lda + kc);
      av[rr][0] = t.x; av[rr][1] = t.y; av[rr][2] = t.z; av[rr][3] = t.w;
    }
#pragma unroll
    for (int kk = 0; kk < 4; ++kk) {
      const float4 t = *(const float4*)(Bm + (kc + kk) * ldb + j4);
      bv[kk][0] = t.x; bv[kk][1] = t.y; bv[kk][2] = t.z; bv[kk][3] = t.w;
    }
#pragma unroll
    for (int rr = 0; rr < 4; ++rr)
#pragma unroll
      for (int cc = 0; cc < 4; ++cc) {
        float s = acc[rr][cc];
#pragma unroll
        for (int kk = 0; kk < 4; ++kk) s += av[rr][kk] * bv[kk][cc];
        acc[rr][cc] = s;
      }
  }
}

__global__ __launch_bounds__(NTHREADS, 2)
void gcrnn_mfma2(const float* __restrict__ x,     // [16384][64]
                 const float* __restrict__ ew,    // [262144]
                 const float* __restrict__ wA,    // [4][1][64]
                 const float* __restrict__ bA,    // [64]
                 const float* __restrict__ wB,    // [4][64][64]
                 const float* __restrict__ bB,    // [64]
                 const float* __restrict__ w1,    // [64][64]
                 const float* __restrict__ b1,    // [64]
                 const float* __restrict__ w2,    // [64][32]
                 const float* __restrict__ b2,    // [32]
                 const float* __restrict__ wfc,   // [2048][4]
                 const float* __restrict__ bfc,   // [4]
                 const int* __restrict__ esrc,
                 const int* __restrict__ edst,
                 float* __restrict__ out)         // [256][4]
{
  __shared__ __align__(16) char smem[SMEM_BYTES];

  f16*   sM1   = (f16*)(smem + OFF_M1);
  f16*   sM2   = (f16*)(smem + OFF_M2);
  f16*   sM3   = (f16*)(smem + OFF_M3);
  f16*   sM1T  = (f16*)(smem + OFF_M1T);
  f16*   sM2T  = (f16*)(smem + OFF_M2T);
  f16*   sTt   = (f16*)(smem + OFF_TT);
  f16*   sZall = (f16*)(smem + OFF_ZALL);
  f16*   sWt   = (f16*)(smem + OFF_WT);
  f16*   sZst  = (f16*)(smem + OFF_ZST);
  float* sLgF  = (float*)(smem + OFF_LGF);
  float* sDeg  = (float*)(smem + OFF_DEG);
  float* sDinv = (float*)(smem + OFF_DINV);
  float* sBsum = (float*)(smem + OFF_BSUM);
  float* sLogit= (float*)(smem + OFF_LOGIT);

  const int b = blockIdx.x, tid = threadIdx.x;
  const int gbase = b * NODES, ebase = b * EPG;
  const int wid = tid >> 6, lane = tid & 63;
  const int lrow = lane & 15, lk = lane >> 4;

  // ---------------- W0: zero + stage ----------------
  for (int idx = tid; idx < 4096; idx += NTHREADS) sLgF[idx] = 0.f;
  for (int idx = tid; idx < 9216 / 4; idx += NTHREADS) ((int*)(smem + OFF_TT))[idx] = 0;
  for (int idx = tid; idx < 5120 / 4; idx += NTHREADS) ((int*)(smem + OFF_ZST))[idx] = 0;
  if (tid < 64) { sDeg[tid] = 0.f; sBsum[tid] = bA[tid] + bB[tid]; }
  // Wt [c][K]: K 0..255 = wB[k][j][c] (K=64k+j), 256..259 = wA, 260..303 = 0
  for (int idx = tid; idx < 64 * 260; idx += NTHREADS) {
    const int k = idx >> 6, c = idx & 63;
    const float v = (k < 256) ? wB[(k >> 6) * 4096 + (k & 63) * 64 + c]
                              : wA[(k - 256) * 64 + c];
    sWt[c * 304 + k] = (f16)v;
  }
  for (int idx = tid; idx < 64 * 44; idx += NTHREADS) {
    const int c = idx / 44, j = idx - c * 44;
    sWt[c * 304 + 260 + j] = (f16)0.f;
  }
  // X^T into sZall[0]: sZall0[t][n] = x[gbase+n][t]  (coalesced global read)
  for (int idx = tid; idx < 4096; idx += NTHREADS) {
    const int n = idx >> 6, t = idx & 63;
    sZall[t * 72 + n] = (f16)x[gbase * 64 + idx];
  }
  __syncthreads();

  // ---------------- Laplacian build (fp32) ----------------
  for (int e = tid; e < EPG; e += NTHREADS)
    atomicAdd(&sDeg[esrc[ebase + e] - gbase], ew[ebase + e]);
  __syncthreads();
  if (tid < 64) { const float d = sDeg[tid]; sDinv[tid] = (d > 0.f) ? rsqrtf(d) : 0.f; }
  __syncthreads();
  for (int e = tid; e < EPG; e += NTHREADS) {
    const int sl = esrc[ebase + e] - gbase, dl = edst[ebase + e] - gbase;
    atomicAdd(&sLgF[dl * 64 + sl], -(sDinv[sl] * ew[ebase + e] * sDinv[dl]));
  }
  __syncthreads();
  // stage fp16 Lambda row-major + transposed
  for (int idx = tid; idx < 4096; idx += NTHREADS) {
    const int i = idx >> 6, j = idx & 63;
    const f16 v = (f16)sLgF[idx];
    sM1[i * 72 + j] = v;
    sM1T[j * 72 + i] = v;
  }
  __syncthreads();

  const int rbP = wid >> 1, cb0 = (wid & 1) * 2;

  // window5: M2 (both layouts) + Z1
  {
    f32x4 d0, d1;
    mm64(sM1T, sM1, rbP, cb0, lrow, lk, d0, d1);     // D = (Lam^2)^T
    stM2s(sM2, d0, rbP, cb0, lrow, lk);
    stM2s(sM2, d1, rbP, cb0 + 1, lrow, lk);
    mm64(sM1, sM1T, rbP, cb0, lrow, lk, d0, d1);     // D = Lam^2
    stM2s(sM2T, d0, rbP, cb0, lrow, lk);
    stM2s(sM2T, d1, rbP, cb0 + 1, lrow, lk);
    mm64(sM1, sZall, rbP, cb0, lrow, lk, d0, d1);    // Z1 = Lam @ X
    stZs(sZall + 64 * 72, d0, rbP, cb0, lrow, lk);
    stZs(sZall + 64 * 72, d1, rbP, cb0 + 1, lrow, lk);
  }
  __syncthreads();
  // window6: M3 + Z2
  {
    f32x4 d0, d1;
    mm64(sM2T, sM1, rbP, cb0, lrow, lk, d0, d1);     // D[p][q] = (Lam M2)[q][p]
    stM3s(sM3, sM1, d0, rbP, cb0, lrow, lk);
    stM3s(sM3, sM1, d1, rbP, cb0 + 1, lrow, lk);
    mm64(sM2, sZall, rbP, cb0, lrow, lk, d0, d1);    // Z2 = M2 @ X
    stZs(sZall + 2 * 64 * 72, d0, rbP, cb0, lrow, lk);
    stZs(sZall + 2 * 64 * 72, d1, rbP, cb0 + 1, lrow, lk);
  }
  __syncthreads();

  // window7: Z3 + register preloads + zero h-buffer A
  f16x8 mfrag[6][2];
  f16x8 wfrag[2][9];
  float bsr[2][4];
  const int fb = wid & 3, half = wid >> 2;           // Phase A assignment
  const int rb0 = (wid >> 2) * 2, cbB = wid & 3;     // Phase B assignment
  {
    f32x4 d0, d1;
    mm64(sM3, sZall, rbP, cb0, lrow, lk, d0, d1);    // Z3 = M3 @ X
    stZs(sZall + 3 * 64 * 72, d0, rbP, cb0, lrow, lk);
    stZs(sZall + 3 * 64 * 72, d1, rbP, cb0 + 1, lrow, lk);
    for (int idx = tid; idx < 9216 / 4; idx += NTHREADS) ((int*)(smem + OFF_M1T))[idx] = 0;
#pragma unroll
    for (int i = 0; i < 6; ++i) {
      const int nb = half * 6 + i;
      const f16* Mb = (const f16*)smem + (nb >> 2) * 4608;  // sM1/sM2/sM3 contiguous
#pragma unroll
      for (int ch = 0; ch < 2; ++ch)
        mfrag[i][ch] = *(const f16x8*)(Mb + ((nb & 3) * 16 + lrow) * 72 + ch * 32 + lk * 8);
    }
#pragma unroll
    for (int u = 0; u < 2; ++u)
#pragma unroll
      for (int ch = 0; ch < 9; ++ch)
        wfrag[u][ch] = *(const f16x8*)(sWt + ((rb0 + u) * 16 + lrow) * 304 + ch * 32 + lk * 8);
#pragma unroll
    for (int u = 0; u < 2; ++u)
#pragma unroll
      for (int r = 0; r < 4; ++r)
        bsr[u][r] = sBsum[(rb0 + u) * 16 + lk * 4 + r];
  }
  __syncthreads();

  // ---------------- scan: 64 steps, 2 barriers each ----------------
  f16* hA = (f16*)(smem + OFF_M1T);
  f16* hB = (f16*)(smem + OFF_M2T);
  const f16* sY1 = sM1;  // Y buffers overlay M buffers (frags already in regs)
  const f16* sY2 = sM2;
  const f16* sY3 = sM3;

  auto step = [&](int t, const f16* hrCur, f16* hrNxt) {
    // ---- Phase A: Yk = Mk @ h  (+ wave7 copies z_t) ----
    if (wid == 7) {
      const int n = lane;
      f16x4 zz;
#pragma unroll
      for (int k = 0; k < 4; ++k) zz[k] = sZall[(k * 64 + t) * 72 + n];
      *(f16x4*)(sZst + n * 40) = zz;
    }
    {
      const f16x8 a0 = *(const f16x8*)(sTt + (fb * 16 + lrow) * 72 + lk * 8);
      const f16x8 a1 = *(const f16x8*)(sTt + (fb * 16 + lrow) * 72 + 32 + lk * 8);
#pragma unroll
      for (int i = 0; i < 6; ++i) {
        f32x4 d = (f32x4){0.f, 0.f, 0.f, 0.f};
        d = mfma16(a0, mfrag[i][0], d);
        d = mfma16(a1, mfrag[i][1], d);
        const int nb = half * 6 + i;
        f16* Yb = (f16*)smem + (nb >> 2) * 4608;
        f16x4 w;
#pragma unroll
        for (int r = 0; r < 4; ++r) w[r] = (f16)d[r];
        *(f16x4*)(Yb + ((nb & 3) * 16 + lrow) * 72 + fb * 16 + lk * 4) = w;
      }
    }
    __syncthreads();
    // ---- Phase B: h' = sigmoid([h|Y1|Y2|Y3|z] @ Wcat + b) ----
    {
      f32x4 p0 = (f32x4){bsr[0][0], bsr[0][1], bsr[0][2], bsr[0][3]};
      f32x4 p1 = (f32x4){bsr[1][0], bsr[1][1], bsr[1][2], bsr[1][3]};
      const int bn = cbB * 16 + lrow;
      f16x8 bb;
      bb = *(const f16x8*)(hrCur + bn * 72 + lk * 8);      p0 = mfma16(wfrag[0][0], bb, p0); p1 = mfma16(wfrag[1][0], bb, p1);
      bb = *(const f16x8*)(hrCur + bn * 72 + 32 + lk * 8); p0 = mfma16(wfrag[0][1], bb, p0); p1 = mfma16(wfrag[1][1], bb, p1);
      bb = *(const f16x8*)(sY1 + bn * 72 + lk * 8);        p0 = mfma16(wfrag[0][2], bb, p0); p1 = mfma16(wfrag[1][2], bb, p1);
      bb = *(const f16x8*)(sY1 + bn * 72 + 32 + lk * 8);   p0 = mfma16(wfrag[0][3], bb, p0); p1 = mfma16(wfrag[1][3], bb, p1);
      bb = *(const f16x8*)(sY2 + bn * 72 + lk * 8);        p0 = mfma16(wfrag[0][4], bb, p0); p1 = mfma16(wfrag[1][4], bb, p1);
      bb = *(const f16x8*)(sY2 + bn * 72 + 32 + lk * 8);   p0 = mfma16(wfrag[0][5], bb, p0); p1 = mfma16(wfrag[1][5], bb, p1);
      bb = *(const f16x8*)(sY3 + bn * 72 + lk * 8);        p0 = mfma16(wfrag[0][6], bb, p0); p1 = mfma16(wfrag[1][6], bb, p1);
      bb = *(const f16x8*)(sY3 + bn * 72 + 32 + lk * 8);   p0 = mfma16(wfrag[0][7], bb, p0); p1 = mfma16(wfrag[1][7], bb, p1);
      bb = *(const f16x8*)(sZst + bn * 40 + lk * 8);       p0 = mfma16(wfrag[0][8], bb, p0); p1 = mfma16(wfrag[1][8], bb, p1);

      float hv[2][4];
#pragma unroll
      for (int r = 0; r < 4; ++r) {
        hv[0][r] = 1.f / (1.f + __expf(-p0[r]));
        hv[1][r] = 1.f / (1.f + __expf(-p1[r]));
      }
#pragma unroll
      for (int u = 0; u < 2; ++u) {
        f16x4 w;
#pragma unroll
        for (int r = 0; r < 4; ++r) w[r] = (f16)hv[u][r];
        *(f16x4*)(hrNxt + bn * 72 + (rb0 + u) * 16 + lk * 4) = w;   // row-major h
#pragma unroll
        for (int r = 0; r < 4; ++r)                                  // h^T scatter
          sTt[((rb0 + u) * 16 + lk * 4 + r) * 72 + bn] = w[r];
      }
    }
    __syncthreads();
  };

#pragma unroll 1
  for (int tt = 0; tt < NSTEPS / 2; ++tt) {
    step(2 * tt, hA, hB);
    step(2 * tt + 1, hB, hA);
  }
  // final h (fp16, row-major) is in hA

  // ---------------- Phase 3: GCN x2 + FC + log_softmax (fp32) ----------------
  float* sLgG = (float*)(smem + OFF_ZALL);            // [64][68]
  float* sT1g = (float*)(smem + OFF_ZALL + 18432);    // [64][68]
  float* sT2g = (float*)(smem + OFF_WT);              // [64][68]

  for (int idx = tid; idx < 64 * 68; idx += NTHREADS) sLgG[idx] = 0.f;
  if (tid < 64) sDeg[tid] = 0.f;
  for (int idx = tid; idx < 4096; idx += NTHREADS) {
    const int n = idx >> 6, c = idx & 63;
    sT1g[n * 68 + c] = (float)hA[n * 72 + c];
  }
  if (tid < 4) sLogit[tid] = bfc[tid];
  __syncthreads();
  for (int e = tid; e < EPG; e += NTHREADS)
    atomicAdd(&sDeg[edst[ebase + e] - gbase], ew[ebase + e]);
  __syncthreads();
  if (tid < 64) sDinv[tid] = rsqrtf(sDeg[tid] + 1.f);
  __syncthreads();
  for (int e = tid; e < EPG; e += NTHREADS) {
    const int sl = esrc[ebase + e] - gbase, dl = edst[ebase + e] - gbase;
    atomicAdd(&sLgG[dl * 68 + sl], sDinv[sl] * ew[ebase + e] * sDinv[dl]);
  }
  __syncthreads();
  if (tid < 64) sLgG[tid * 68 + tid] += sDinv[tid] * sDinv[tid];
  __syncthreads();

  const bool isTile = tid < 256;
  const int i4 = ((tid >> 4) & 15) * 4;
  const int j4 = (tid & 15) * 4;

  // xw1 = h @ w1 (w1 global) -> sT2g
  if (isTile) {
    float m[4][4] = {};
    mm4x4_acc<64>(m, sT1g, 68, i4, w1, 64, j4);
#pragma unroll
    for (int rr = 0; rr < 4; ++rr)
      *(float4*)(sT2g + (i4 + rr) * 68 + j4) = make_float4(m[rr][0], m[rr][1], m[rr][2], m[rr][3]);
  }
  __syncthreads();
  // z1 = relu(Ag @ xw1 + b1) -> sT1g
  if (isTile) {
    float m[4][4] = {};
    mm4x4_acc<64>(m, sLgG, 68, i4, sT2g, 68, j4);
#pragma unroll
    for (int rr = 0; rr < 4; ++rr) {
      float4 o;
      o.x = fmaxf(m[rr][0] + b1[j4 + 0], 0.f);
      o.y = fmaxf(m[rr][1] + b1[j4 + 1], 0.f);
      o.z = fmaxf(m[rr][2] + b1[j4 + 2], 0.f);
      o.w = fmaxf(m[rr][3] + b1[j4 + 3], 0.f);
      *(float4*)(sT1g + (i4 + rr) * 68 + j4) = o;
    }
  }
  __syncthreads();
  // xw2 = z1 @ w2 (global) -> sT2g cols 0..31
  if (isTile && j4 < 32) {
    float m[4][4] = {};
    mm4x4_acc<64>(m, sT1g, 68, i4, w2, 32, j4);
#pragma unroll
    for (int rr = 0; rr < 4; ++rr)
      *(float4*)(sT2g + (i4 + rr) * 68 + j4) = make_float4(m[rr][0], m[rr][1], m[rr][2], m[rr][3]);
  }
  __syncthreads();
  // z2 = relu(Ag @ xw2 + b2) -> sT1g cols 0..31
  if (isTile && j4 < 32) {
    float m[4][4] = {};
    mm4x4_acc<64>(m, sLgG, 68, i4, sT2g, 68, j4);
#pragma unroll
    for (int rr = 0; rr < 4; ++rr) {
      float4 o;
      o.x = fmaxf(m[rr][0] + b2[j4 + 0], 0.f);
      o.y = fmaxf(m[rr][1] + b2[j4 + 1], 0.f);
      o.z = fmaxf(m[rr][2] + b2[j4 + 2], 0.f);
      o.w = fmaxf(m[rr][3] + b2[j4 + 3], 0.f);
      *(float4*)(sT1g + (i4 + rr) * 68 + j4) = o;
    }
  }
  __syncthreads();

  // FC + log_softmax
  float p0 = 0.f, p1 = 0.f, p2 = 0.f, p3 = 0.f;
  for (int f = tid; f < 2048; f += NTHREADS) {
    const int n = f >> 5, c = f & 31;
    const float v = sT1g[n * 68 + c];
    const float4 wv = *(const float4*)(wfc + f * 4);
    p0 += v * wv.x; p1 += v * wv.y; p2 += v * wv.z; p3 += v * wv.w;
  }
#pragma unroll
  for (int off = 1; off < 64; off <<= 1) {
    p0 += __shfl_xor(p0, off);
    p1 += __shfl_xor(p1, off);
    p2 += __shfl_xor(p2, off);
    p3 += __shfl_xor(p3, off);
  }
  if ((tid & 63) == 0) {
    atomicAdd(&sLogit[0], p0);
    atomicAdd(&sLogit[1], p1);
    atomicAdd(&sLogit[2], p2);
    atomicAdd(&sLogit[3], p3);
  }
  __syncthreads();
  if (tid == 0) {
    const float l0 = sLogit[0], l1 = sLogit[1], l2 = sLogit[2], l3 = sLogit[3];
    const float mx = fmaxf(fmaxf(l0, l1), fmaxf(l2, l3));
    const float s = expf(l0 - mx) + expf(l1 - mx) + expf(l2 - mx) + expf(l3 - mx);
    const float lse = mx + logf(s);
    out[b * 4 + 0] = l0 - lse;
    out[b * 4 + 1] = l1 - lse;
    out[b * 4 + 2] = l2 - lse;
    out[b * 4 + 3] = l3 - lse;
  }
}

extern "C" void kernel_launch(void* const* d_in, const int* in_sizes, int n_in,
                              void* d_out, int out_size, void* d_ws, size_t ws_size,
                              hipStream_t stream) {
  gcrnn_mfma2<<<NBLOCKS, NTHREADS, 0, stream>>>(
      (const float*)d_in[0],   // x
      (const float*)d_in[1],   // edge_weight
      (const float*)d_in[2],   // wA
      (const float*)d_in[3],   // bA
      (const float*)d_in[4],   // wB
      (const float*)d_in[5],   // bB
      (const float*)d_in[6],   // w1
      (const float*)d_in[7],   // b1
      (const float*)d_in[8],   // w2
      (const float*)d_in[9],   // b2
      (const float*)d_in[10],  // wfc
      (const float*)d_in[11],  // bfc
      (const int*)d_in[12],    // edge_src
      (const int*)d_in[13],    // edge_dst
      (float*)d_out);
}